// Round 1
// baseline (2422.826 us; speedup 1.0000x reference)
//
#include <hip/hip_runtime.h>
#include <math.h>

#define N_NODES  100000
#define N_EDGES  1600000
#define N_GRAPHS 1000
#define NPG      100

__device__ __forceinline__ float elu_f(float x) {
    return x > 0.0f ? x : expm1f(x);
}

// ---------------- degree ----------------
__global__ __launch_bounds__(256) void deg_init_k(float* __restrict__ deg) {
    int i = blockIdx.x * 256 + threadIdx.x;
    if (i < N_NODES) deg[i] = 1.0f;   // self loop
}

__global__ __launch_bounds__(256) void deg_acc_k(const int* __restrict__ ei, float* __restrict__ deg) {
    int e = blockIdx.x * 256 + threadIdx.x;
    if (e < N_EDGES) atomicAdd(&deg[ei[N_EDGES + e]], 1.0f);
}

// ---------------- generic node GEMM: C = post(A[M,K] @ W[N,K]^T) ----------------
// post: +bias (opt), elu (opt), row-scale by rsqrt(deg) (opt), duplicate write (opt)
template<int K, int N, int NT, int TN, int TC, bool ELU, bool SCALE, bool DUP, bool BIAS>
__global__ __launch_bounds__(256) void gemm_k(
    const float* __restrict__ A, const float* __restrict__ W,
    const float* __restrict__ bias, const float* __restrict__ deg,
    float* __restrict__ C, float* __restrict__ C2, int M)
{
    constexpr int CG = N / TC;              // col groups
    static_assert((NT / TN) * CG == 256, "thread mapping");
    constexpr int KP = K + 4;               // Xs row pad
    constexpr int NP = N + 4;               // Ws row pad (keeps 16B align, breaks bank conflicts)

    __shared__ float Xs[NT * KP];
    __shared__ float Ws[K * NP];

    const int t = threadIdx.x;
    const int node0 = blockIdx.x * NT;

    // load W [N][K] transposed into Ws[k][j]
    for (int idx = t; idx < N * K; idx += 256) {
        int j = idx / K, k = idx % K;       // coalesced global read
        Ws[k * NP + j] = W[idx];
    }
    // load X tile (fully coalesced: gn*K + k == node0*K + idx)
    for (int idx = t; idx < NT * K; idx += 256) {
        int n = idx / K, k = idx % K;
        int gn = node0 + n;
        Xs[n * KP + k] = (gn < M) ? A[(size_t)gn * K + k] : 0.0f;
    }
    __syncthreads();

    const int ng = t / CG;
    const int cg = t % CG;

    float acc[TN][TC];
    #pragma unroll
    for (int i = 0; i < TN; ++i)
        #pragma unroll
        for (int j = 0; j < TC; ++j) acc[i][j] = 0.0f;

    #pragma unroll 4
    for (int k = 0; k < K; ++k) {
        float xv[TN];
        #pragma unroll
        for (int i = 0; i < TN; ++i) xv[i] = Xs[(ng * TN + i) * KP + k];
        const float* wr = &Ws[k * NP + cg * TC];
        float wv[TC];
        if constexpr (TC % 4 == 0) {
            #pragma unroll
            for (int j4 = 0; j4 < TC / 4; ++j4) {
                float4 v = *(const float4*)(wr + 4 * j4);
                wv[4*j4+0] = v.x; wv[4*j4+1] = v.y; wv[4*j4+2] = v.z; wv[4*j4+3] = v.w;
            }
        } else {
            float2 v = *(const float2*)wr;
            wv[0] = v.x; wv[1] = v.y;
        }
        #pragma unroll
        for (int j = 0; j < TC; ++j)
            #pragma unroll
            for (int i = 0; i < TN; ++i)
                acc[i][j] = fmaf(xv[i], wv[j], acc[i][j]);
    }

    #pragma unroll
    for (int i = 0; i < TN; ++i) {
        int gn = node0 + ng * TN + i;
        if (gn >= M) continue;
        float scale = 1.0f;
        if constexpr (SCALE) scale = rsqrtf(deg[gn]);
        #pragma unroll
        for (int j = 0; j < TC; ++j) {
            float v = acc[i][j];
            if constexpr (BIAS) v += bias[cg * TC + j];
            if constexpr (ELU)  v = elu_f(v);
            if constexpr (SCALE) v *= scale;
            size_t o = (size_t)gn * N + cg * TC + j;
            C[o] = v;
            if constexpr (DUP) C2[o] = v;
        }
    }
}

// ---------------- edge scatter: agg[dst] += c[src]  (F feats, F/4 threads/edge) ----------------
template<int F>
__global__ __launch_bounds__(256) void edge_k(const int* __restrict__ ei,
                                              const float* __restrict__ c,
                                              float* __restrict__ agg)
{
    constexpr int TPE = F / 4;
    int gid = blockIdx.x * 256 + threadIdx.x;
    int e = gid / TPE;
    int q = gid % TPE;
    if (e >= N_EDGES) return;
    int s = ei[e];
    int d = ei[N_EDGES + e];
    float4 v = *(const float4*)(c + (size_t)s * F + q * 4);
    float* a = agg + (size_t)d * F + q * 4;
    atomicAdd(a + 0, v.x);
    atomicAdd(a + 1, v.y);
    atomicAdd(a + 2, v.z);
    atomicAdd(a + 3, v.w);
}

// ---------------- gc1 combine: h2[n,j] = elu(dis_n * sum_b w1[n,h*4+b]*agg1[n,b*16+f] + bias[j]) ----------------
__global__ __launch_bounds__(256) void combine1_k(const float* __restrict__ w1,
                                                  const float* __restrict__ agg,
                                                  const float* __restrict__ deg,
                                                  const float* __restrict__ bias,
                                                  float* __restrict__ h2, int M)
{
    int gid = blockIdx.x * 256 + threadIdx.x;
    int n = gid >> 7, j = gid & 127;
    if (n >= M) return;
    int hh = j >> 4, f = j & 15;
    const float* wr = w1 + (size_t)n * 32 + hh * 4;
    const float* ar = agg + (size_t)n * 64 + f;
    float s = wr[0] * ar[0] + wr[1] * ar[16] + wr[2] * ar[32] + wr[3] * ar[48];
    s = s * rsqrtf(deg[n]) + bias[j];
    h2[(size_t)n * 128 + j] = elu_f(s);
}

// ---------------- gc2 combine + elu + L2 normalize -> h out (wave per node) ----------------
__global__ __launch_bounds__(256) void final_k(const float* __restrict__ w2,
                                               const float* __restrict__ agg2,
                                               const float* __restrict__ deg,
                                               const float* __restrict__ bias,
                                               float* __restrict__ hout, int M)
{
    int wv = (blockIdx.x * 256 + threadIdx.x) >> 6;
    int lane = threadIdx.x & 63;
    if (wv >= M) return;
    int n = wv;
    int hh = lane >> 3, f = lane & 7;
    const float* wr = w2 + (size_t)n * 32 + hh * 4;
    const float* ar = agg2 + (size_t)n * 32 + f;
    float s = wr[0] * ar[0] + wr[1] * ar[8] + wr[2] * ar[16] + wr[3] * ar[24];
    s = s * rsqrtf(deg[n]) + bias[lane];
    s = elu_f(s);
    float tot = s * s;
    #pragma unroll
    for (int m = 1; m < 64; m <<= 1) tot += __shfl_xor(tot, m, 64);
    float inv = 1.0f / fmaxf(sqrtf(tot), 1e-12f);
    hout[(size_t)n * 64 + lane] = s * inv;
}

// ---------------- per-graph tail: z_a, attention softmax, z_c ----------------
__global__ __launch_bounds__(128) void graph_k(const float* __restrict__ h,
                                               const float* __restrict__ z_e,
                                               const float* __restrict__ aw,
                                               const float* __restrict__ ab,
                                               const float* __restrict__ fcgw,
                                               const float* __restrict__ fcgb,
                                               const float* __restrict__ fccgw,
                                               const float* __restrict__ fccgb,
                                               float* __restrict__ z_a,
                                               float* __restrict__ z_c)
{
    __shared__ float Hs[NPG * 64];
    __shared__ float sumh[64], wsh[64], lg[NPG], ex[NPG];
    __shared__ float red[2];
    int g = blockIdx.x, t = threadIdx.x;
    const float* hg = h + (size_t)g * NPG * 64;
    for (int idx = t; idx < NPG * 64; idx += 128) Hs[idx] = hg[idx];
    __syncthreads();

    if (t < 64) {
        float s = 0.0f;
        for (int n = 0; n < NPG; ++n) s += Hs[n * 64 + t];
        sumh[t] = s;
    }
    if (t >= 64 && t < 64 + NPG - 36) { /* nothing: keep simple */ }
    __syncthreads();

    if (t < 64) {
        float acc = fcgb[t];
        for (int f = 0; f < 64; ++f) acc = fmaf(sumh[f], fcgw[t * 64 + f], acc);
        z_a[(size_t)g * 64 + t] = acc;
    }
    if (t < NPG) {
        float zd = 0.0f;
        for (int q = 0; q < 32; ++q) zd = fmaf(z_e[(size_t)g * 32 + q], aw[64 + q], zd);
        float dot = 0.0f;
        for (int k0 = 0; k0 < 64; ++k0) {
            int k = (k0 + t) & 63;            // rotate start: avoids LDS bank serialization
            dot = fmaf(Hs[t * 64 + k], aw[k], dot);
        }
        lg[t] = dot + zd + ab[0] + 1e-16f;
    }
    __syncthreads();

    if (t < 64) {
        float m = -INFINITY;
        for (int n = t; n < NPG; n += 64) m = fmaxf(m, lg[n]);
        #pragma unroll
        for (int o = 1; o < 64; o <<= 1) m = fmaxf(m, __shfl_xor(m, o, 64));
        if (t == 0) red[0] = m;
    }
    __syncthreads();
    float m = red[0];
    if (t < NPG) ex[t] = expf(lg[t] - m);
    __syncthreads();
    if (t < 64) {
        float s = 0.0f;
        for (int n = t; n < NPG; n += 64) s += ex[n];
        #pragma unroll
        for (int o = 1; o < 64; o <<= 1) s += __shfl_xor(s, o, 64);
        if (t == 0) red[1] = s + 1e-16f;
    }
    __syncthreads();
    float inv_denom = 1.0f / red[1];
    if (t < 64) {
        float a = 0.0f;
        for (int n = 0; n < NPG; ++n) a = fmaf(ex[n], Hs[n * 64 + t], a);
        wsh[t] = a * inv_denom;
    }
    __syncthreads();
    if (t < 64) {
        float acc = fccgb[t];
        for (int f = 0; f < 64; ++f) acc = fmaf(wsh[f], fccgw[t * 64 + f], acc);
        z_c[(size_t)g * 64 + t] = acc;
    }
}

extern "C" void kernel_launch(void* const* d_in, const int* in_sizes, int n_in,
                              void* d_out, int out_size, void* d_ws, size_t ws_size,
                              hipStream_t stream)
{
    const float* x     = (const float*)d_in[0];
    const int*   ei    = (const int*)d_in[1];
    // d_in[2]=batch, d_in[3]=n_atoms: structure is regular (100 nodes/graph), unused
    const float* z_e   = (const float*)d_in[4];
    const float* nfc_w = (const float*)d_in[5];
    const float* nfc_b = (const float*)d_in[6];
    const float* g1bw  = (const float*)d_in[7];
    const float* g1cw  = (const float*)d_in[8];
    const float* g1cb  = (const float*)d_in[9];
    const float* g1b   = (const float*)d_in[10];
    const float* g2bw  = (const float*)d_in[11];
    const float* g2cw  = (const float*)d_in[12];
    const float* g2cb  = (const float*)d_in[13];
    const float* g2b   = (const float*)d_in[14];
    const float* aw    = (const float*)d_in[15];
    const float* ab    = (const float*)d_in[16];
    const float* fcgw  = (const float*)d_in[17];
    const float* fcgb  = (const float*)d_in[18];
    const float* fccgw = (const float*)d_in[19];
    const float* fccgb = (const float*)d_in[20];

    // workspace layout (floats); total 28,902,400 fl = 115.6 MB
    float* ws   = (float*)d_ws;
    float* deg  = ws;                    // 102,400
    float* h1   = ws + 102400;           // 12.8M  (reused as h2)
    float* c1   = h1 + 12800000;         // 6.4M   (reused: c2 @ +0, agg2 @ +3.2M)
    float* agg1 = c1 + 6400000;          // 6.4M   (reused as w2)
    float* w1   = agg1 + 6400000;        // 3.2M
    float* c2   = c1;
    float* agg2 = c1 + 3200000;
    float* w2   = agg1;

    float* z_a  = (float*)d_out;
    float* z_c  = z_a + (size_t)N_GRAPHS * 64;
    float* hout = z_a + (size_t)2 * N_GRAPHS * 64;

    deg_init_k<<<(N_NODES + 255) / 256, 256, 0, stream>>>(deg);
    deg_acc_k<<<(N_EDGES + 255) / 256, 256, 0, stream>>>(ei, deg);

    // h1 = elu(x @ nfc_w^T + nfc_b)                       [100k,64]x[64,128]
    gemm_k<64, 128, 64, 4, 8, true, false, false, true>
        <<<(N_NODES + 63) / 64, 256, 0, stream>>>(x, nfc_w, nfc_b, deg, h1, nullptr, N_NODES);
    // c1 = dis * (h1 @ g1bw^T); agg1 = c1                 [100k,128]x[128,64]
    gemm_k<128, 64, 32, 2, 4, false, true, true, false>
        <<<(N_NODES + 31) / 32, 256, 0, stream>>>(h1, g1bw, nullptr, deg, c1, agg1, N_NODES);
    // w1 = h1 @ g1cw^T + g1cb                             [100k,128]x[128,32]
    gemm_k<128, 32, 64, 4, 2, false, false, false, true>
        <<<(N_NODES + 63) / 64, 256, 0, stream>>>(h1, g1cw, g1cb, deg, w1, nullptr, N_NODES);
    // agg1[dst] += c1[src]
    edge_k<64><<<(N_EDGES * 16) / 256, 256, 0, stream>>>(ei, c1, agg1);
    // h2 = elu(dis*combine(w1, agg1) + g1_bias)  -> into h1 buffer
    combine1_k<<<(N_NODES * 128) / 256, 256, 0, stream>>>(w1, agg1, deg, g1b, h1, N_NODES);
    // c2 = dis * (h2 @ g2bw^T); agg2 = c2                 [100k,128]x[128,32]
    gemm_k<128, 32, 64, 4, 2, false, true, true, false>
        <<<(N_NODES + 63) / 64, 256, 0, stream>>>(h1, g2bw, nullptr, deg, c2, agg2, N_NODES);
    // w2 = h2 @ g2cw^T + g2cb
    gemm_k<128, 32, 64, 4, 2, false, false, false, true>
        <<<(N_NODES + 63) / 64, 256, 0, stream>>>(h1, g2cw, g2cb, deg, w2, nullptr, N_NODES);
    // agg2[dst] += c2[src]
    edge_k<32><<<(N_EDGES * 8) / 256, 256, 0, stream>>>(ei, c2, agg2);
    // h = normalize(elu(dis*combine(w2, agg2) + g2_bias))
    final_k<<<(N_NODES + 3) / 4, 256, 0, stream>>>(w2, agg2, deg, g2b, hout, N_NODES);
    // per-graph pooling + attention heads
    graph_k<<<N_GRAPHS, 128, 0, stream>>>(hout, z_e, aw, ab, fcgw, fcgb, fccgw, fccgb, z_a, z_c);
}

// Round 3
// 945.436 us; speedup vs baseline: 2.5627x; 2.5627x over previous
//
#include <hip/hip_runtime.h>
#include <math.h>

#define N_NODES  100000
#define N_EDGES  1600000
#define N_GRAPHS 1000
#define NPG      100
#define SCAN_T   1024
#define SCAN_CH  ((N_NODES + SCAN_T - 1) / SCAN_T)   // 98

__device__ __forceinline__ float elu_f(float x) {
    return x > 0.0f ? x : expm1f(x);
}

// ---------------- CSR build ----------------
__global__ __launch_bounds__(256) void zero_cnt_k(int* __restrict__ cnt) {
    int i = blockIdx.x * 256 + threadIdx.x;
    if (i < N_NODES) cnt[i] = 0;
}

__global__ __launch_bounds__(256) void count_k(const int* __restrict__ ei, int* __restrict__ cnt) {
    int e = blockIdx.x * 256 + threadIdx.x;
    if (e < N_EDGES) atomicAdd(&cnt[ei[N_EDGES + e]], 1);
}

// single-block exclusive scan over cnt -> starts, cursor; also dis = rsqrt(1+cnt)
__global__ __launch_bounds__(SCAN_T) void scan_k(const int* __restrict__ cnt,
                                                 int* __restrict__ starts,
                                                 int* __restrict__ cursor,
                                                 float* __restrict__ dis)
{
    __shared__ int part[SCAN_T];
    int t = threadIdx.x;
    int base = t * SCAN_CH;
    int s = 0;
    for (int i = 0; i < SCAN_CH; ++i) {
        int idx = base + i;
        if (idx < N_NODES) s += cnt[idx];
    }
    part[t] = s;
    __syncthreads();
    for (int off = 1; off < SCAN_T; off <<= 1) {
        int v = (t >= off) ? part[t - off] : 0;
        __syncthreads();
        part[t] += v;
        __syncthreads();
    }
    int run = (t == 0) ? 0 : part[t - 1];
    for (int i = 0; i < SCAN_CH; ++i) {
        int idx = base + i;
        if (idx < N_NODES) {
            starts[idx] = run;
            cursor[idx] = run;
            dis[idx] = rsqrtf(1.0f + (float)cnt[idx]);
            run += cnt[idx];
        }
    }
}

__global__ __launch_bounds__(256) void fill_k(const int* __restrict__ ei,
                                              int* __restrict__ cursor,
                                              int* __restrict__ srclist)
{
    int e = blockIdx.x * 256 + threadIdx.x;
    if (e < N_EDGES) {
        int s = ei[e];
        int d = ei[N_EDGES + e];
        int pos = atomicAdd(&cursor[d], 1);
        srclist[pos] = s;
    }
}

// ---------------- generic node GEMM: C = post(A[M,K] @ W[N,K]^T) ----------------
template<int K, int N, int NT, int TN, int TC, bool ELU, bool SCALE, bool BIAS>
__global__ __launch_bounds__(256) void gemm_k(
    const float* __restrict__ A, const float* __restrict__ W,
    const float* __restrict__ bias, const float* __restrict__ dis,
    float* __restrict__ C, int M)
{
    constexpr int CG = N / TC;
    static_assert((NT / TN) * CG == 256, "thread mapping");
    constexpr int KP = K + 4;
    constexpr int NP = N + 4;

    __shared__ float Xs[NT * KP];
    __shared__ float Ws[K * NP];

    const int t = threadIdx.x;
    const int node0 = blockIdx.x * NT;

    for (int idx = t; idx < N * K; idx += 256) {
        int j = idx / K, k = idx % K;
        Ws[k * NP + j] = W[idx];
    }
    for (int idx = t; idx < NT * K; idx += 256) {
        int n = idx / K, k = idx % K;
        int gn = node0 + n;
        Xs[n * KP + k] = (gn < M) ? A[(size_t)gn * K + k] : 0.0f;
    }
    __syncthreads();

    const int ng = t / CG;
    const int cg = t % CG;

    float acc[TN][TC];
    #pragma unroll
    for (int i = 0; i < TN; ++i)
        #pragma unroll
        for (int j = 0; j < TC; ++j) acc[i][j] = 0.0f;

    #pragma unroll 4
    for (int k = 0; k < K; ++k) {
        float xv[TN];
        #pragma unroll
        for (int i = 0; i < TN; ++i) xv[i] = Xs[(ng * TN + i) * KP + k];
        const float* wr = &Ws[k * NP + cg * TC];
        float wv[TC];
        if constexpr (TC % 4 == 0) {
            #pragma unroll
            for (int j4 = 0; j4 < TC / 4; ++j4) {
                float4 v = *(const float4*)(wr + 4 * j4);
                wv[4*j4+0] = v.x; wv[4*j4+1] = v.y; wv[4*j4+2] = v.z; wv[4*j4+3] = v.w;
            }
        } else {
            float2 v = *(const float2*)wr;
            wv[0] = v.x; wv[1] = v.y;
        }
        #pragma unroll
        for (int j = 0; j < TC; ++j)
            #pragma unroll
            for (int i = 0; i < TN; ++i)
                acc[i][j] = fmaf(xv[i], wv[j], acc[i][j]);
    }

    #pragma unroll
    for (int i = 0; i < TN; ++i) {
        int gn = node0 + ng * TN + i;
        if (gn >= M) continue;
        float scale = 1.0f;
        if constexpr (SCALE) scale = dis[gn];
        #pragma unroll
        for (int j = 0; j < TC; ++j) {
            float v = acc[i][j];
            if constexpr (BIAS) v += bias[cg * TC + j];
            if constexpr (ELU)  v = elu_f(v);
            if constexpr (SCALE) v *= scale;
            C[(size_t)gn * N + cg * TC + j] = v;
        }
    }
}

// ---------------- layer-1 gather + combine + elu (divergence-safe, no shfl) ----------------
// block = 256 = 16 nodes x 16 threads; thread owns 4 features (float4) of c (64 feats)
__global__ __launch_bounds__(256) void gather1_k(
    const int* __restrict__ starts, const int* __restrict__ cnt,
    const int* __restrict__ srclist, const float* __restrict__ c,
    const float* __restrict__ w1, const float* __restrict__ dis,
    const float* __restrict__ bias, float* __restrict__ h2)
{
    __shared__ float aggS[16][68];
    __shared__ float w1S[16][32];

    const int t = threadIdx.x;
    const int nn = t >> 4;            // node within block
    const int q  = t & 15;            // feature quad
    const int n  = blockIdx.x * 16 + nn;

    // stage w1 tile (coalesced): 16 nodes x 32 floats = 512
    {
        int i0 = t * 2;
        int wn = i0 >> 5, wj = i0 & 31;
        float2 v = *(const float2*)(w1 + (size_t)(blockIdx.x * 16 + wn) * 32 + wj);
        w1S[wn][wj] = v.x;
        w1S[wn][wj + 1] = v.y;
    }

    const int s0 = starts[n];
    const int cn = cnt[n];
    float4 a = *(const float4*)(c + (size_t)n * 64 + q * 4);   // self term
    for (int j = 0; j < cn; ++j) {
        int src = srclist[s0 + j];                              // broadcast within group
        float4 v = *(const float4*)(c + (size_t)src * 64 + q * 4);
        a.x += v.x; a.y += v.y; a.z += v.z; a.w += v.w;
    }
    aggS[nn][q * 4 + 0] = a.x;
    aggS[nn][q * 4 + 1] = a.y;
    aggS[nn][q * 4 + 2] = a.z;
    aggS[nn][q * 4 + 3] = a.w;
    __syncthreads();

    // combine: thread (nn,q) computes outputs j = r*16 + q for r = 0..7 (f = q)
    float ab[4];
    #pragma unroll
    for (int b = 0; b < 4; ++b) ab[b] = aggS[nn][b * 16 + q];
    const float dn = dis[n];
    float* out = h2 + (size_t)n * 128;
    #pragma unroll
    for (int r = 0; r < 8; ++r) {
        float s = 0.0f;
        #pragma unroll
        for (int b = 0; b < 4; ++b) s = fmaf(w1S[nn][r * 4 + b], ab[b], s);
        out[r * 16 + q] = elu_f(s * dn + bias[r * 16 + q]);
    }
}

// ---------------- layer-2 gather + combine + elu + L2 normalize (divergence-safe) ----------------
// block = 256 = 8 nodes x 32 threads; thread owns 1 feature of c (32 feats)
__global__ __launch_bounds__(256) void gather2_k(
    const int* __restrict__ starts, const int* __restrict__ cnt,
    const int* __restrict__ srclist, const float* __restrict__ c,
    const float* __restrict__ w2, const float* __restrict__ dis,
    const float* __restrict__ bias, float* __restrict__ hout)
{
    __shared__ float aggS[8][36];
    __shared__ float w2S[8][32];

    const int t = threadIdx.x;
    const int nn = t >> 5;            // node within block
    const int q  = t & 31;            // feature
    const int n  = blockIdx.x * 8 + nn;

    // stage w2 tile (coalesced): 8 nodes x 32 floats = 256
    w2S[t >> 5][t & 31] = w2[(size_t)(blockIdx.x * 8 + (t >> 5)) * 32 + (t & 31)];

    const int s0 = starts[n];
    const int cn = cnt[n];
    float a = c[(size_t)n * 32 + q];                            // self term
    for (int j = 0; j < cn; ++j) {
        int src = srclist[s0 + j];
        a += c[(size_t)src * 32 + q];
    }
    aggS[nn][q] = a;
    __syncthreads();

    // combine: thread (nn,q) computes outputs j1 = q, j2 = q + 32
    const int f  = q & 7;
    const int hh = q >> 3;
    float ab[4];
    #pragma unroll
    for (int b = 0; b < 4; ++b) ab[b] = aggS[nn][b * 8 + f];
    const float dn = dis[n];
    float s1 = 0.0f, s2 = 0.0f;
    #pragma unroll
    for (int b = 0; b < 4; ++b) {
        s1 = fmaf(w2S[nn][hh * 4 + b], ab[b], s1);
        s2 = fmaf(w2S[nn][(hh + 4) * 4 + b], ab[b], s2);
    }
    s1 = elu_f(s1 * dn + bias[q]);
    s2 = elu_f(s2 * dn + bias[q + 32]);

    // L2 norm across the node's 64 outputs: reduce s1^2+s2^2 over the aligned 32-thread group
    float tot = s1 * s1 + s2 * s2;
    #pragma unroll
    for (int o = 1; o < 32; o <<= 1) tot += __shfl_xor(tot, o, 64);
    float inv = 1.0f / fmaxf(sqrtf(tot), 1e-12f);
    hout[(size_t)n * 64 + q]      = s1 * inv;
    hout[(size_t)n * 64 + 32 + q] = s2 * inv;
}

// ---------------- per-graph tail: z_a, attention softmax, z_c ----------------
__global__ __launch_bounds__(128) void graph_k(const float* __restrict__ h,
                                               const float* __restrict__ z_e,
                                               const float* __restrict__ aw,
                                               const float* __restrict__ ab,
                                               const float* __restrict__ fcgw,
                                               const float* __restrict__ fcgb,
                                               const float* __restrict__ fccgw,
                                               const float* __restrict__ fccgb,
                                               float* __restrict__ z_a,
                                               float* __restrict__ z_c)
{
    __shared__ float Hs[NPG * 64];
    __shared__ float sumh[64], wsh[64], lg[NPG], ex[NPG];
    __shared__ float red[2];
    int g = blockIdx.x, t = threadIdx.x;
    const float* hg = h + (size_t)g * NPG * 64;
    for (int idx = t; idx < NPG * 64; idx += 128) Hs[idx] = hg[idx];
    __syncthreads();

    if (t < 64) {
        float s = 0.0f;
        for (int n = 0; n < NPG; ++n) s += Hs[n * 64 + t];
        sumh[t] = s;
    }
    __syncthreads();

    if (t < 64) {
        float acc = fcgb[t];
        for (int f = 0; f < 64; ++f) acc = fmaf(sumh[f], fcgw[t * 64 + f], acc);
        z_a[(size_t)g * 64 + t] = acc;
    }
    if (t < NPG) {
        float zd = 0.0f;
        for (int q = 0; q < 32; ++q) zd = fmaf(z_e[(size_t)g * 32 + q], aw[64 + q], zd);
        float dot = 0.0f;
        for (int k0 = 0; k0 < 64; ++k0) {
            int k = (k0 + t) & 63;
            dot = fmaf(Hs[t * 64 + k], aw[k], dot);
        }
        lg[t] = dot + zd + ab[0] + 1e-16f;
    }
    __syncthreads();

    if (t < 64) {
        float m = -INFINITY;
        for (int n = t; n < NPG; n += 64) m = fmaxf(m, lg[n]);
        #pragma unroll
        for (int o = 1; o < 64; o <<= 1) m = fmaxf(m, __shfl_xor(m, o, 64));
        if (t == 0) red[0] = m;
    }
    __syncthreads();
    float m = red[0];
    if (t < NPG) ex[t] = expf(lg[t] - m);
    __syncthreads();
    if (t < 64) {
        float s = 0.0f;
        for (int n = t; n < NPG; n += 64) s += ex[n];
        #pragma unroll
        for (int o = 1; o < 64; o <<= 1) s += __shfl_xor(s, o, 64);
        if (t == 0) red[1] = s + 1e-16f;
    }
    __syncthreads();
    float inv_denom = 1.0f / red[1];
    if (t < 64) {
        float a = 0.0f;
        for (int n = 0; n < NPG; ++n) a = fmaf(ex[n], Hs[n * 64 + t], a);
        wsh[t] = a * inv_denom;
    }
    __syncthreads();
    if (t < 64) {
        float acc = fccgb[t];
        for (int f = 0; f < 64; ++f) acc = fmaf(wsh[f], fccgw[t * 64 + f], acc);
        z_c[(size_t)g * 64 + t] = acc;
    }
}

extern "C" void kernel_launch(void* const* d_in, const int* in_sizes, int n_in,
                              void* d_out, int out_size, void* d_ws, size_t ws_size,
                              hipStream_t stream)
{
    const float* x     = (const float*)d_in[0];
    const int*   ei    = (const int*)d_in[1];
    const float* z_e   = (const float*)d_in[4];
    const float* nfc_w = (const float*)d_in[5];
    const float* nfc_b = (const float*)d_in[6];
    const float* g1bw  = (const float*)d_in[7];
    const float* g1cw  = (const float*)d_in[8];
    const float* g1cb  = (const float*)d_in[9];
    const float* g1b   = (const float*)d_in[10];
    const float* g2bw  = (const float*)d_in[11];
    const float* g2cw  = (const float*)d_in[12];
    const float* g2cb  = (const float*)d_in[13];
    const float* g2b   = (const float*)d_in[14];
    const float* aw    = (const float*)d_in[15];
    const float* ab    = (const float*)d_in[16];
    const float* fcgw  = (const float*)d_in[17];
    const float* fcgb  = (const float*)d_in[18];
    const float* fccgw = (const float*)d_in[19];
    const float* fccgb = (const float*)d_in[20];

    // workspace layout: 24.5M floats = 98.0 MB
    float* ws      = (float*)d_ws;
    float* dis     = ws;                          // 102400 fl
    int*   cnt     = (int*)(ws + 102400);         // 102400
    int*   starts  = cnt + 102400;                // 102400
    int*   cursor  = starts + 102400;             // 102400
    int*   srclist = cursor + 102400;             // 1,600,000
    float* h1      = (float*)(srclist + 1600000); // 12.8M  (reused as h2)
    float* c1      = h1 + 12800000;               // 6.4M   (reused: c2 @ +0, w2 @ +3.2M)
    float* w1      = c1 + 6400000;                // 3.2M
    float* c2      = c1;
    float* w2      = c1 + 3200000;

    float* z_a  = (float*)d_out;
    float* z_c  = z_a + (size_t)N_GRAPHS * 64;
    float* hout = z_a + (size_t)2 * N_GRAPHS * 64;

    // CSR build (shared by both layers)
    zero_cnt_k<<<(N_NODES + 255) / 256, 256, 0, stream>>>(cnt);
    count_k<<<(N_EDGES + 255) / 256, 256, 0, stream>>>(ei, cnt);
    scan_k<<<1, SCAN_T, 0, stream>>>(cnt, starts, cursor, dis);
    fill_k<<<(N_EDGES + 255) / 256, 256, 0, stream>>>(ei, cursor, srclist);

    // h1 = elu(x @ nfc_w^T + nfc_b)                       [100k,64]x[64,128]
    gemm_k<64, 128, 64, 4, 8, true, false, true>
        <<<(N_NODES + 63) / 64, 256, 0, stream>>>(x, nfc_w, nfc_b, dis, h1, N_NODES);
    // c1 = dis * (h1 @ g1bw^T)                            [100k,128]x[128,64]
    gemm_k<128, 64, 32, 2, 4, false, true, false>
        <<<(N_NODES + 31) / 32, 256, 0, stream>>>(h1, g1bw, nullptr, dis, c1, N_NODES);
    // w1 = h1 @ g1cw^T + g1cb                             [100k,128]x[128,32]
    gemm_k<128, 32, 64, 4, 2, false, false, true>
        <<<(N_NODES + 63) / 64, 256, 0, stream>>>(h1, g1cw, g1cb, dis, w1, N_NODES);
    // h2 = elu(dis * combine(w1, gather(c1)) + g1_bias)  -> h1 buffer
    gather1_k<<<N_NODES / 16, 256, 0, stream>>>(starts, cnt, srclist, c1, w1, dis, g1b, h1);
    // c2 = dis * (h2 @ g2bw^T)                            [100k,128]x[128,32]
    gemm_k<128, 32, 64, 4, 2, false, true, false>
        <<<(N_NODES + 63) / 64, 256, 0, stream>>>(h1, g2bw, nullptr, dis, c2, N_NODES);
    // w2 = h2 @ g2cw^T + g2cb
    gemm_k<128, 32, 64, 4, 2, false, false, true>
        <<<(N_NODES + 63) / 64, 256, 0, stream>>>(h1, g2cw, g2cb, dis, w2, N_NODES);
    // h = normalize(elu(dis * combine(w2, gather(c2)) + g2_bias))
    gather2_k<<<N_NODES / 8, 256, 0, stream>>>(starts, cnt, srclist, c2, w2, dis, g2b, hout);
    // per-graph pooling + attention heads
    graph_k<<<N_GRAPHS, 128, 0, stream>>>(hout, z_e, aw, ab, fcgw, fcgb, fccgw, fccgb, z_a, z_c);
}

// Round 4
// 652.776 us; speedup vs baseline: 3.7116x; 1.4483x over previous
//
#include <hip/hip_runtime.h>
#include <math.h>

#define N_NODES  100000
#define N_EDGES  1600000
#define N_GRAPHS 1000
#define NPG      100
#define NB_SCAN  ((N_NODES + 255) / 256)   // 391

__device__ __forceinline__ float elu_f(float x) {
    return x > 0.0f ? x : expm1f(x);
}

// ---------------- CSR build ----------------
__global__ __launch_bounds__(256) void zero_cnt_k(int* __restrict__ cnt) {
    int i = blockIdx.x * 256 + threadIdx.x;
    if (i < N_NODES) cnt[i] = 0;
}

__global__ __launch_bounds__(256) void count_k(const int* __restrict__ ei, int* __restrict__ cnt) {
    int e = blockIdx.x * 256 + threadIdx.x;
    if (e < N_EDGES) atomicAdd(&cnt[ei[N_EDGES + e]], 1);
}

// 3-kernel device-wide exclusive scan over cnt
__global__ __launch_bounds__(256) void scan_bsum_k(const int* __restrict__ cnt, int* __restrict__ bsum) {
    __shared__ int red[256];
    int t = threadIdx.x;
    int i = blockIdx.x * 256 + t;
    red[t] = (i < N_NODES) ? cnt[i] : 0;
    __syncthreads();
    #pragma unroll
    for (int off = 128; off > 0; off >>= 1) {
        if (t < off) red[t] += red[t + off];
        __syncthreads();
    }
    if (t == 0) bsum[blockIdx.x] = red[0];
}

__global__ __launch_bounds__(512) void scan_boff_k(const int* __restrict__ bsum, int* __restrict__ boff) {
    __shared__ int s[512];
    int t = threadIdx.x;
    s[t] = (t < NB_SCAN) ? bsum[t] : 0;
    __syncthreads();
    #pragma unroll
    for (int off = 1; off < 512; off <<= 1) {
        int u = (t >= off) ? s[t - off] : 0;
        __syncthreads();
        s[t] += u;
        __syncthreads();
    }
    boff[t] = (t == 0) ? 0 : s[t - 1];
}

__global__ __launch_bounds__(256) void scan_apply_k(const int* __restrict__ cnt,
                                                    const int* __restrict__ boff,
                                                    int* __restrict__ starts,
                                                    int* __restrict__ cursor,
                                                    float* __restrict__ dis)
{
    __shared__ int s[256];
    int t = threadIdx.x;
    int i = blockIdx.x * 256 + t;
    int v = (i < N_NODES) ? cnt[i] : 0;
    s[t] = v;
    __syncthreads();
    #pragma unroll
    for (int off = 1; off < 256; off <<= 1) {
        int u = (t >= off) ? s[t - off] : 0;
        __syncthreads();
        s[t] += u;
        __syncthreads();
    }
    if (i < N_NODES) {
        int ex = boff[blockIdx.x] + s[t] - v;
        starts[i] = ex;
        cursor[i] = ex;
        dis[i] = rsqrtf(1.0f + (float)v);
    }
}

__global__ __launch_bounds__(256) void fill_k(const int* __restrict__ ei,
                                              int* __restrict__ cursor,
                                              int* __restrict__ srclist)
{
    int e = blockIdx.x * 256 + threadIdx.x;
    if (e < N_EDGES) {
        int s = ei[e];
        int d = ei[N_EDGES + e];
        int pos = atomicAdd(&cursor[d], 1);
        srclist[pos] = s;
    }
}

// ---------------- generic node GEMM: C = post(A[M,K] @ W[N,K]^T) ----------------
template<int K, int N, int NT, int TN, int TC, bool ELU, bool SCALE, bool BIAS>
__global__ __launch_bounds__(256) void gemm_k(
    const float* __restrict__ A, const float* __restrict__ W,
    const float* __restrict__ bias, const float* __restrict__ dis,
    float* __restrict__ C, int M)
{
    constexpr int CG = N / TC;
    static_assert((NT / TN) * CG == 256, "thread mapping");
    constexpr int KP = K + 4;
    constexpr int NP = N + 4;

    __shared__ float Xs[NT * KP];
    __shared__ float Ws[K * NP];

    const int t = threadIdx.x;
    const int node0 = blockIdx.x * NT;

    for (int idx = t; idx < N * K; idx += 256) {
        int j = idx / K, k = idx % K;
        Ws[k * NP + j] = W[idx];
    }
    for (int idx = t; idx < NT * K; idx += 256) {
        int n = idx / K, k = idx % K;
        int gn = node0 + n;
        Xs[n * KP + k] = (gn < M) ? A[(size_t)gn * K + k] : 0.0f;
    }
    __syncthreads();

    const int ng = t / CG;
    const int cg = t % CG;

    float acc[TN][TC];
    #pragma unroll
    for (int i = 0; i < TN; ++i)
        #pragma unroll
        for (int j = 0; j < TC; ++j) acc[i][j] = 0.0f;

    #pragma unroll 4
    for (int k = 0; k < K; ++k) {
        float xv[TN];
        #pragma unroll
        for (int i = 0; i < TN; ++i) xv[i] = Xs[(ng * TN + i) * KP + k];
        const float* wr = &Ws[k * NP + cg * TC];
        float wv[TC];
        if constexpr (TC % 4 == 0) {
            #pragma unroll
            for (int j4 = 0; j4 < TC / 4; ++j4) {
                float4 v = *(const float4*)(wr + 4 * j4);
                wv[4*j4+0] = v.x; wv[4*j4+1] = v.y; wv[4*j4+2] = v.z; wv[4*j4+3] = v.w;
            }
        } else {
            float2 v = *(const float2*)wr;
            wv[0] = v.x; wv[1] = v.y;
        }
        #pragma unroll
        for (int j = 0; j < TC; ++j)
            #pragma unroll
            for (int i = 0; i < TN; ++i)
                acc[i][j] = fmaf(xv[i], wv[j], acc[i][j]);
    }

    #pragma unroll
    for (int i = 0; i < TN; ++i) {
        int gn = node0 + ng * TN + i;
        if (gn >= M) continue;
        float scale = 1.0f;
        if constexpr (SCALE) scale = dis[gn];
        #pragma unroll
        for (int j = 0; j < TC; ++j) {
            float v = acc[i][j];
            if constexpr (BIAS) v += bias[cg * TC + j];
            if constexpr (ELU)  v = elu_f(v);
            if constexpr (SCALE) v *= scale;
            C[(size_t)gn * N + cg * TC + j] = v;
        }
    }
}

// ---------------- layer-1 gather + combine + elu (divergence-safe, no shfl) ----------------
// block = 256 = 16 nodes x 16 threads; thread owns 4 features (float4) of c (64 feats)
__global__ __launch_bounds__(256) void gather1_k(
    const int* __restrict__ starts, const int* __restrict__ cnt,
    const int* __restrict__ srclist, const float* __restrict__ c,
    const float* __restrict__ w1, const float* __restrict__ dis,
    const float* __restrict__ bias, float* __restrict__ h2)
{
    __shared__ float aggS[16][68];
    __shared__ float w1S[16][32];

    const int t = threadIdx.x;
    const int nn = t >> 4;            // node within block
    const int q  = t & 15;            // feature quad
    const int n  = blockIdx.x * 16 + nn;

    // stage w1 tile (coalesced): 16 nodes x 32 floats = 512
    {
        int i0 = t * 2;
        int wn = i0 >> 5, wj = i0 & 31;
        float2 v = *(const float2*)(w1 + (size_t)(blockIdx.x * 16 + wn) * 32 + wj);
        w1S[wn][wj] = v.x;
        w1S[wn][wj + 1] = v.y;
    }

    const int s0 = starts[n];
    const int cn = cnt[n];
    float4 a = *(const float4*)(c + (size_t)n * 64 + q * 4);   // self term
    for (int j = 0; j < cn; ++j) {
        int src = srclist[s0 + j];                              // broadcast within group
        float4 v = *(const float4*)(c + (size_t)src * 64 + q * 4);
        a.x += v.x; a.y += v.y; a.z += v.z; a.w += v.w;
    }
    aggS[nn][q * 4 + 0] = a.x;
    aggS[nn][q * 4 + 1] = a.y;
    aggS[nn][q * 4 + 2] = a.z;
    aggS[nn][q * 4 + 3] = a.w;
    __syncthreads();

    // combine: thread (nn,q) computes outputs j = r*16 + q for r = 0..7 (f = q)
    float ab[4];
    #pragma unroll
    for (int b = 0; b < 4; ++b) ab[b] = aggS[nn][b * 16 + q];
    const float dn = dis[n];
    float* out = h2 + (size_t)n * 128;
    #pragma unroll
    for (int r = 0; r < 8; ++r) {
        float s = 0.0f;
        #pragma unroll
        for (int b = 0; b < 4; ++b) s = fmaf(w1S[nn][r * 4 + b], ab[b], s);
        out[r * 16 + q] = elu_f(s * dn + bias[r * 16 + q]);
    }
}

// ---------------- layer-2 gather + combine + elu + L2 normalize (divergence-safe) ----------------
// block = 256 = 8 nodes x 32 threads; thread owns 1 feature of c (32 feats)
__global__ __launch_bounds__(256) void gather2_k(
    const int* __restrict__ starts, const int* __restrict__ cnt,
    const int* __restrict__ srclist, const float* __restrict__ c,
    const float* __restrict__ w2, const float* __restrict__ dis,
    const float* __restrict__ bias, float* __restrict__ hout)
{
    __shared__ float aggS[8][36];
    __shared__ float w2S[8][32];

    const int t = threadIdx.x;
    const int nn = t >> 5;            // node within block
    const int q  = t & 31;            // feature
    const int n  = blockIdx.x * 8 + nn;

    // stage w2 tile (coalesced): 8 nodes x 32 floats = 256
    w2S[t >> 5][t & 31] = w2[(size_t)(blockIdx.x * 8 + (t >> 5)) * 32 + (t & 31)];

    const int s0 = starts[n];
    const int cn = cnt[n];
    float a = c[(size_t)n * 32 + q];                            // self term
    for (int j = 0; j < cn; ++j) {
        int src = srclist[s0 + j];
        a += c[(size_t)src * 32 + q];
    }
    aggS[nn][q] = a;
    __syncthreads();

    // combine: thread (nn,q) computes outputs j1 = q, j2 = q + 32
    const int f  = q & 7;
    const int hh = q >> 3;
    float ab[4];
    #pragma unroll
    for (int b = 0; b < 4; ++b) ab[b] = aggS[nn][b * 8 + f];
    const float dn = dis[n];
    float s1 = 0.0f, s2 = 0.0f;
    #pragma unroll
    for (int b = 0; b < 4; ++b) {
        s1 = fmaf(w2S[nn][hh * 4 + b], ab[b], s1);
        s2 = fmaf(w2S[nn][(hh + 4) * 4 + b], ab[b], s2);
    }
    s1 = elu_f(s1 * dn + bias[q]);
    s2 = elu_f(s2 * dn + bias[q + 32]);

    // L2 norm across the node's 64 outputs: reduce s1^2+s2^2 over the aligned 32-thread group
    float tot = s1 * s1 + s2 * s2;
    #pragma unroll
    for (int o = 1; o < 32; o <<= 1) tot += __shfl_xor(tot, o, 64);
    float inv = 1.0f / fmaxf(sqrtf(tot), 1e-12f);
    hout[(size_t)n * 64 + q]      = s1 * inv;
    hout[(size_t)n * 64 + 32 + q] = s2 * inv;
}

// ---------------- per-graph tail: z_a, attention softmax, z_c ----------------
__global__ __launch_bounds__(128) void graph_k(const float* __restrict__ h,
                                               const float* __restrict__ z_e,
                                               const float* __restrict__ aw,
                                               const float* __restrict__ ab,
                                               const float* __restrict__ fcgw,
                                               const float* __restrict__ fcgb,
                                               const float* __restrict__ fccgw,
                                               const float* __restrict__ fccgb,
                                               float* __restrict__ z_a,
                                               float* __restrict__ z_c)
{
    __shared__ float Hs[NPG * 64];
    __shared__ float sumh[64], wsh[64], lg[NPG], ex[NPG];
    __shared__ float red[2];
    int g = blockIdx.x, t = threadIdx.x;
    const float* hg = h + (size_t)g * NPG * 64;
    for (int idx = t; idx < NPG * 64; idx += 128) Hs[idx] = hg[idx];
    __syncthreads();

    if (t < 64) {
        float s = 0.0f;
        for (int n = 0; n < NPG; ++n) s += Hs[n * 64 + t];
        sumh[t] = s;
    }
    __syncthreads();

    if (t < 64) {
        float acc = fcgb[t];
        for (int f = 0; f < 64; ++f) acc = fmaf(sumh[f], fcgw[t * 64 + f], acc);
        z_a[(size_t)g * 64 + t] = acc;
    }
    if (t < NPG) {
        float zd = 0.0f;
        for (int q = 0; q < 32; ++q) zd = fmaf(z_e[(size_t)g * 32 + q], aw[64 + q], zd);
        float dot = 0.0f;
        for (int k0 = 0; k0 < 64; ++k0) {
            int k = (k0 + t) & 63;
            dot = fmaf(Hs[t * 64 + k], aw[k], dot);
        }
        lg[t] = dot + zd + ab[0] + 1e-16f;
    }
    __syncthreads();

    if (t < 64) {
        float m = -INFINITY;
        for (int n = t; n < NPG; n += 64) m = fmaxf(m, lg[n]);
        #pragma unroll
        for (int o = 1; o < 64; o <<= 1) m = fmaxf(m, __shfl_xor(m, o, 64));
        if (t == 0) red[0] = m;
    }
    __syncthreads();
    float m = red[0];
    if (t < NPG) ex[t] = expf(lg[t] - m);
    __syncthreads();
    if (t < 64) {
        float s = 0.0f;
        for (int n = t; n < NPG; n += 64) s += ex[n];
        #pragma unroll
        for (int o = 1; o < 64; o <<= 1) s += __shfl_xor(s, o, 64);
        if (t == 0) red[1] = s + 1e-16f;
    }
    __syncthreads();
    float inv_denom = 1.0f / red[1];
    if (t < 64) {
        float a = 0.0f;
        for (int n = 0; n < NPG; ++n) a = fmaf(ex[n], Hs[n * 64 + t], a);
        wsh[t] = a * inv_denom;
    }
    __syncthreads();
    if (t < 64) {
        float acc = fccgb[t];
        for (int f = 0; f < 64; ++f) acc = fmaf(wsh[f], fccgw[t * 64 + f], acc);
        z_c[(size_t)g * 64 + t] = acc;
    }
}

extern "C" void kernel_launch(void* const* d_in, const int* in_sizes, int n_in,
                              void* d_out, int out_size, void* d_ws, size_t ws_size,
                              hipStream_t stream)
{
    const float* x     = (const float*)d_in[0];
    const int*   ei    = (const int*)d_in[1];
    const float* z_e   = (const float*)d_in[4];
    const float* nfc_w = (const float*)d_in[5];
    const float* nfc_b = (const float*)d_in[6];
    const float* g1bw  = (const float*)d_in[7];
    const float* g1cw  = (const float*)d_in[8];
    const float* g1cb  = (const float*)d_in[9];
    const float* g1b   = (const float*)d_in[10];
    const float* g2bw  = (const float*)d_in[11];
    const float* g2cw  = (const float*)d_in[12];
    const float* g2cb  = (const float*)d_in[13];
    const float* g2b   = (const float*)d_in[14];
    const float* aw    = (const float*)d_in[15];
    const float* ab    = (const float*)d_in[16];
    const float* fcgw  = (const float*)d_in[17];
    const float* fcgb  = (const float*)d_in[18];
    const float* fccgw = (const float*)d_in[19];
    const float* fccgb = (const float*)d_in[20];

    // workspace layout: ~24.5M floats = 98 MB
    float* ws      = (float*)d_ws;
    float* dis     = ws;                          // 102400 fl
    int*   cnt     = (int*)(ws + 102400);         // 102400
    int*   starts  = cnt + 102400;                // 102400
    int*   cursor  = starts + 102400;             // 102400
    int*   bsum    = cursor + 102400;             // 512
    int*   boff    = bsum + 512;                  // 512
    int*   srclist = boff + 512;                  // 1,600,000
    float* h1      = (float*)(srclist + 1600000); // 12.8M  (reused as h2)
    float* c1      = h1 + 12800000;               // 6.4M   (reused: c2 @ +0, w2 @ +3.2M)
    float* w1      = c1 + 6400000;                // 3.2M
    float* c2      = c1;
    float* w2      = c1 + 3200000;

    float* z_a  = (float*)d_out;
    float* z_c  = z_a + (size_t)N_GRAPHS * 64;
    float* hout = z_a + (size_t)2 * N_GRAPHS * 64;

    // CSR build (shared by both layers)
    zero_cnt_k<<<(N_NODES + 255) / 256, 256, 0, stream>>>(cnt);
    count_k<<<(N_EDGES + 255) / 256, 256, 0, stream>>>(ei, cnt);
    scan_bsum_k<<<NB_SCAN, 256, 0, stream>>>(cnt, bsum);
    scan_boff_k<<<1, 512, 0, stream>>>(bsum, boff);
    scan_apply_k<<<NB_SCAN, 256, 0, stream>>>(cnt, boff, starts, cursor, dis);
    fill_k<<<(N_EDGES + 255) / 256, 256, 0, stream>>>(ei, cursor, srclist);

    // h1 = elu(x @ nfc_w^T + nfc_b)                       [100k,64]x[64,128]
    gemm_k<64, 128, 64, 4, 8, true, false, true>
        <<<(N_NODES + 63) / 64, 256, 0, stream>>>(x, nfc_w, nfc_b, dis, h1, N_NODES);
    // c1 = dis * (h1 @ g1bw^T)                            [100k,128]x[128,64]
    gemm_k<128, 64, 32, 2, 4, false, true, false>
        <<<(N_NODES + 31) / 32, 256, 0, stream>>>(h1, g1bw, nullptr, dis, c1, N_NODES);
    // w1 = h1 @ g1cw^T + g1cb                             [100k,128]x[128,32]
    gemm_k<128, 32, 64, 4, 2, false, false, true>
        <<<(N_NODES + 63) / 64, 256, 0, stream>>>(h1, g1cw, g1cb, dis, w1, N_NODES);
    // h2 = elu(dis * combine(w1, gather(c1)) + g1_bias)  -> h1 buffer
    gather1_k<<<N_NODES / 16, 256, 0, stream>>>(starts, cnt, srclist, c1, w1, dis, g1b, h1);
    // c2 = dis * (h2 @ g2bw^T)                            [100k,128]x[128,32]
    gemm_k<128, 32, 64, 4, 2, false, true, false>
        <<<(N_NODES + 63) / 64, 256, 0, stream>>>(h1, g2bw, nullptr, dis, c2, N_NODES);
    // w2 = h2 @ g2cw^T + g2cb
    gemm_k<128, 32, 64, 4, 2, false, false, true>
        <<<(N_NODES + 63) / 64, 256, 0, stream>>>(h1, g2cw, g2cb, dis, w2, N_NODES);
    // h = normalize(elu(dis * combine(w2, gather(c2)) + g2_bias))
    gather2_k<<<N_NODES / 8, 256, 0, stream>>>(starts, cnt, srclist, c2, w2, dis, g2b, hout);
    // per-graph pooling + attention heads
    graph_k<<<N_GRAPHS, 128, 0, stream>>>(hout, z_e, aw, ab, fcgw, fcgb, fccgw, fccgb, z_a, z_c);
}